// Round 6
// baseline (480.981 us; speedup 1.0000x reference)
//
#include <hip/hip_runtime.h>

#define N_NODES 100000
#define N_EDGES 500000
#define D 256
#define CAP 32          // bucket capacity per (node, relation); λ=5 ⇒ P(deg>32)≈1e-15
#define BM 64           // rows per block
#define AG_STRIDE 2056  // gather-tile stride in shorts (4KB + 16B pad -> banks t*4)

typedef __bf16 bf16x8 __attribute__((ext_vector_type(8)));
typedef float  f32x4  __attribute__((ext_vector_type(4)));

// ---- bf16 helpers (manual, RNE) -------------------------------------------
__device__ __forceinline__ unsigned short f2bf(float f) {
    unsigned int u = __float_as_uint(f);
    u += 0x7fffu + ((u >> 16) & 1u);
    return (unsigned short)(u >> 16);
}
__device__ __forceinline__ float bf2f(unsigned short b) {
    return __uint_as_float(((unsigned int)b) << 16);
}

// ---- async global->LDS, 16B per lane (dest = uniform base + lane*16) ------
__device__ __forceinline__ void glds16(const unsigned short* g, unsigned short* l) {
    __builtin_amdgcn_global_load_lds(
        (const __attribute__((address_space(1))) unsigned int*)g,
        (__attribute__((address_space(3))) unsigned int*)l,
        16, 0, 0);
}

// ---------------------------------------------------------------------------
// Prep kernel, WAVE-granular role interleave.
// Round-6 tweak: convert loads made fully contiguous (two float4 streams at
// base+lane*4 and base+256+lane*4) instead of the stride-32B interleave.
// W-role writes Wt PRE-SWIZZLED (k' = k ^ (((n>>1)&3)<<3)) for linear-dest
// global_load_lds staging in the GEMM (m173 pattern).
// ---------------------------------------------------------------------------
#define PREP_BLOCKS 17188   // ceil(22*3125 waves / 4 per block)

__global__ __launch_bounds__(256) void prep_kernel(
    const float* __restrict__ x, unsigned short* __restrict__ xb,
    const float* __restrict__ Ws, const float* __restrict__ W1,
    const float* __restrict__ W2, unsigned short* __restrict__ Wt,
    const int* __restrict__ src1, const int* __restrict__ dst1,
    const int* __restrict__ src2, const int* __restrict__ dst2,
    int* __restrict__ cnt1, int* __restrict__ cnt2,
    int* __restrict__ bkt1, int* __restrict__ bkt2)
{
    const int wid  = blockIdx.x * 4 + (threadIdx.x >> 6);  // global wave id
    const int lane = threadIdx.x & 63;
    const int group = wid / 22;
    const int pos   = wid - group * 22;

    if (pos < 16) {
        // ---- convert role: x fp32 -> xb bf16, 8 elems/lane, contiguous ----
        int cw = group * 16 + pos;
        if (cw >= 50000) return;
        size_t base = (size_t)cw * 512;
        float4 a = *(const float4*)(x + base + lane * 4);
        float4 c = *(const float4*)(x + base + 256 + lane * 4);
        ushort4 oa, oc;
        oa.x = f2bf(a.x); oa.y = f2bf(a.y); oa.z = f2bf(a.z); oa.w = f2bf(a.w);
        oc.x = f2bf(c.x); oc.y = f2bf(c.y); oc.z = f2bf(c.z); oc.w = f2bf(c.w);
        *(ushort4*)(xb + base + lane * 4) = oa;
        *(ushort4*)(xb + base + 256 + lane * 4) = oc;
    } else if (pos < 21) {
        // ---- bucket role: 1 edge/lane, cnt/bkt atomics (L2-resident) ----
        int bw = group * 5 + (pos - 16);
        int e = bw * 64 + lane;
        if (e >= 2 * N_EDGES) return;
        bool r2 = (e >= N_EDGES);
        const int* src = r2 ? src2 : src1;
        const int* dst = r2 ? dst2 : dst1;
        int* cnt = r2 ? cnt2 : cnt1;
        int* bkt = r2 ? bkt2 : bkt1;
        int ei = r2 ? e - N_EDGES : e;
        int s = src[ei], d = dst[ei];
        int p = atomicAdd(&cnt[d], 1);
        if (p < CAP) bkt[d * CAP + p] = s;
    } else {
        // ---- W-prep role: Wt[n][k^swz] = bf16(scale_k * W[k%256][n]) ----
        int idx = group * 64 + lane;
        if (idx >= 3 * D * D) return;
        int k = idx >> 8;
        int n = idx & (D - 1);
        const float* W = (k < D) ? Ws : (k < 2 * D ? W1 : W2);
        float scale = (k < D) ? 1.1f : 1.0f;
        int dk = k ^ ((((n >> 1) & 3)) << 3);   // pre-swizzle 16B chunk slot
        Wt[(size_t)n * (3 * D) + dk] = f2bf(W[(size_t)(k & (D - 1)) * D + n] * scale);
    }
}

// ---------------------------------------------------------------------------
// Fused gather + MFMA GEMM, round-6: PHASE-SPLIT gather (fixes pipeline-depth
// mismatch of rounds 4/5: 8-MFMA phase (~60cy) can't hide ~700cy L3 gather
// latency -> 24 exposed barrier drains/block, MfmaUtil 7%).
//   out = relu( [xb | gather1(xb) | gather2(xb)] @ Wt^T + bias )
// Structure per block (BM=64, 512 thr):
//   prologue glds (A0,B0) -> GATHER PHASE rel1 (round-0 pattern: one wave-task
//   per node, 8 full 512B rows in flight, shfl ids; results ds_write'd into
//   Agth in swizzled tile layout) -> barrier -> k-loop 0..15 (self tiles glds
//   dbuf; gather tiles read DIRECTLY from Agth; one barrier/iter) -> GATHER
//   PHASE rel2 (reuses Agth; B16 glds in flight across it) -> barrier ->
//   k-loop 16..23 -> epilogue.
// The k-loop holds NO gather state: ~70 unified regs, no spill. Latency is
// concentrated in 2 deep-MLP gather phases, overlapped by the co-resident
// block (LDS 72KB -> 2 blocks/CU).
// Agth tile pad +16B: banks t*4 -> conflict-free frag reads (same pattern as
// rounds 3-5 which measured 0 conflicts).
// ---------------------------------------------------------------------------
__global__ __launch_bounds__(512, 4) void gemm_kernel(
    const unsigned short* __restrict__ xb,
    const int* __restrict__ cnt1, const int* __restrict__ cnt2,
    const int* __restrict__ bkt1, const int* __restrict__ bkt2,
    const unsigned short* __restrict__ Wt,   // [256 n][768 k] bf16, PRE-SWIZZLED
    const float* __restrict__ bias, float* __restrict__ out)
{
    __shared__ unsigned short Agth[8 * AG_STRIDE];   // 32.9 KB gather tiles
    __shared__ unsigned short Aslf[2][BM * 32];      // 2 x 4 KB self tiles
    __shared__ unsigned short Blds[2][256 * 32];     // 2 x 16 KB B tiles

    const int tid  = threadIdx.x;
    const int lane = tid & 63;
    const int wave = tid >> 6;          // 0..7
    const int quad = lane >> 4;
    const int l15  = lane & 15;
    const int m0 = blockIdx.x * BM;
    const int wm = (wave >> 2) * 32;    // 2 m-waves x 4 n-waves
    const int wn = (wave & 3) * 64;
    const int swz = (l15 >> 1) & 3;     // read-side chunk swizzle (row>>1)&3

    // glds source geometry (wave slab of 16 rows; lane -> row,chunk)
    const int gr   = lane >> 2;
    const int gch  = lane & 3;
    const int gswz = (lane >> 3) & 3;   // (row>>1)&3 within slab
    int mSelf = m0 + (wave << 4) + gr;  // waves 0..3 stage A (16 rows each)
    if (mSelf >= N_NODES) mSelf = N_NODES - 1;
    const unsigned short* aSelfSrc = xb + (size_t)mSelf * D + ((gch ^ gswz) << 3);
    const unsigned short* bSrc0 = Wt + (size_t)((wave << 4) + gr) * (3 * D) + (gch << 3);
    const unsigned short* bSrc1 = bSrc0 + (size_t)128 * (3 * D);

    // ---- gather phase: one wave-task per node; full 512B row loads --------
    auto gather_rel = [&](const int* __restrict__ cnt, const int* __restrict__ bkt) {
        #pragma unroll 1
        for (int i = 0; i < 8; ++i) {
            const int n = (wave << 3) + i;              // local node 0..63
            int g = m0 + n; if (g >= N_NODES) g = N_NODES - 1;
            int c = cnt[g]; if (c > CAP) c = CAP;       // wave-uniform
            int sid = (lane < c) ? bkt[(size_t)g * CAP + lane] : 0;
            float a0 = 0.f, a1 = 0.f, a2 = 0.f, a3 = 0.f;
            ushort4 v[8];
            #pragma unroll
            for (int t = 0; t < 8; ++t)                 // 8 rows in flight
                if (t < c) v[t] = *(const ushort4*)(xb + (size_t)__shfl(sid, t) * D + lane * 4);
            #pragma unroll
            for (int t = 0; t < 8; ++t)
                if (t < c) {
                    a0 += bf2f(v[t].x); a1 += bf2f(v[t].y);
                    a2 += bf2f(v[t].z); a3 += bf2f(v[t].w);
                }
            for (int e = 8; e < c; ++e) {               // tail P(deg>8)≈7%
                ushort4 tv = *(const ushort4*)(xb + (size_t)__shfl(sid, e) * D + lane * 4);
                a0 += bf2f(tv.x); a1 += bf2f(tv.y); a2 += bf2f(tv.z); a3 += bf2f(tv.w);
            }
            ushort4 o;
            o.x = f2bf(a0); o.y = f2bf(a1); o.z = f2bf(a2); o.w = f2bf(a3);
            // lane covers k=lane*4..+3: tile=lane>>3, chunk=(lane>>1)&3
            const int tq = lane >> 3;
            const int qp = ((lane >> 1) & 3) ^ ((n >> 1) & 3);
            *(ushort4*)(Agth + tq * AG_STRIDE + n * 32 + qp * 8 + (lane & 1) * 4) = o;
        }
    };

    // ---- MFMA on one k-tile ----
    f32x4 acc[2][4] = {};
    auto mfma_tile = [&](const unsigned short* Ab, const unsigned short* Bb) {
        bf16x8 b0f = *(const bf16x8*)(Bb + (wn +  0 + l15) * 32 + ((quad ^ swz) * 8));
        bf16x8 b1f = *(const bf16x8*)(Bb + (wn + 16 + l15) * 32 + ((quad ^ swz) * 8));
        bf16x8 b2f = *(const bf16x8*)(Bb + (wn + 32 + l15) * 32 + ((quad ^ swz) * 8));
        bf16x8 b3f = *(const bf16x8*)(Bb + (wn + 48 + l15) * 32 + ((quad ^ swz) * 8));
        #pragma unroll
        for (int i = 0; i < 2; ++i) {
            bf16x8 afi = *(const bf16x8*)(Ab + (wm + i * 16 + l15) * 32 + ((quad ^ swz) * 8));
            acc[i][0] = __builtin_amdgcn_mfma_f32_16x16x32_bf16(afi, b0f, acc[i][0], 0, 0, 0);
            acc[i][1] = __builtin_amdgcn_mfma_f32_16x16x32_bf16(afi, b1f, acc[i][1], 0, 0, 0);
            acc[i][2] = __builtin_amdgcn_mfma_f32_16x16x32_bf16(afi, b2f, acc[i][2], 0, 0, 0);
            acc[i][3] = __builtin_amdgcn_mfma_f32_16x16x32_bf16(afi, b3f, acc[i][3], 0, 0, 0);
        }
    };

    // ---- prologue: tile-0 staging in flight across gather phase 1 ----
    if (wave < 4) glds16(aSelfSrc, &Aslf[0][wave * 512]);
    glds16(bSrc0, &Blds[0][wave * 512]);
    glds16(bSrc1, &Blds[0][4096 + wave * 512]);

    gather_rel(cnt1, bkt1);             // fills Agth = k-tiles 8..15
    __syncthreads();                    // drains prologue glds + orders Agth

    // ---- k-loop part 1: tiles 0..15 ----
    for (int kt = 0; kt < 16; ++kt) {
        const int ktn = kt + 1;
        if (ktn < 8 && wave < 4)
            glds16(aSelfSrc + ktn * 32, &Aslf[ktn & 1][wave * 512]);
        if (ktn < 16) {
            glds16(bSrc0 + ktn * 32, &Blds[ktn & 1][wave * 512]);
            glds16(bSrc1 + ktn * 32, &Blds[ktn & 1][4096 + wave * 512]);
        }
        const unsigned short* Ab = (kt < 8) ? &Aslf[kt & 1][0] : (Agth + (kt - 8) * AG_STRIDE);
        mfma_tile(Ab, &Blds[kt & 1][0]);
        __syncthreads();
    }

    // ---- gather phase 2 (rel2), B16 staging in flight across it ----
    glds16(bSrc0 + 16 * 32, &Blds[0][wave * 512]);
    glds16(bSrc1 + 16 * 32, &Blds[0][4096 + wave * 512]);
    gather_rel(cnt2, bkt2);             // overwrites Agth = k-tiles 16..23
    __syncthreads();

    // ---- k-loop part 2: tiles 16..23 ----
    for (int kt = 16; kt < 24; ++kt) {
        const int ktn = kt + 1;
        if (ktn < 24) {
            glds16(bSrc0 + ktn * 32, &Blds[ktn & 1][wave * 512]);
            glds16(bSrc1 + ktn * 32, &Blds[ktn & 1][4096 + wave * 512]);
        }
        mfma_tile(Agth + (kt - 16) * AG_STRIDE, &Blds[kt & 1][0]);
        __syncthreads();
    }

    // ---- epilogue: D layout col=lane&15, row=quad*4+reg (m89/m91) ----
    #pragma unroll
    for (int j = 0; j < 4; ++j) {
        int col = wn + j * 16 + l15;
        float bj = bias[col];
        #pragma unroll
        for (int i = 0; i < 2; ++i) {
            int rb = m0 + wm + i * 16 + quad * 4;
            #pragma unroll
            for (int r = 0; r < 4; ++r) {
                int m = rb + r;
                if (m < N_NODES)
                    __builtin_nontemporal_store(
                        fmaxf(acc[i][j][r] + bj, 0.f),
                        out + (size_t)m * D + col);
            }
        }
    }
}

extern "C" void kernel_launch(void* const* d_in, const int* in_sizes, int n_in,
                              void* d_out, int out_size, void* d_ws, size_t ws_size,
                              hipStream_t stream) {
    const float* x    = (const float*)d_in[0];
    const float* Ws   = (const float*)d_in[1];
    const float* W1   = (const float*)d_in[2];
    const float* W2   = (const float*)d_in[3];
    const float* bias = (const float*)d_in[4];
    const int* src1   = (const int*)d_in[5];
    const int* dst1   = (const int*)d_in[6];
    const int* src2   = (const int*)d_in[7];
    const int* dst2   = (const int*)d_in[8];
    float* out = (float*)d_out;

    // Workspace layout (total 78.4 MB):
    char* p = (char*)d_ws;
    unsigned short* xb  = (unsigned short*)p; p += (size_t)N_NODES * D * 2;  // 51.2 MB
    int* cnt1 = (int*)p; p += (size_t)N_NODES * 4;                           // 0.4 MB
    int* cnt2 = (int*)p; p += (size_t)N_NODES * 4;                           // 0.4 MB
    int* bkt1 = (int*)p; p += (size_t)N_NODES * CAP * 4;                     // 12.8 MB
    int* bkt2 = (int*)p; p += (size_t)N_NODES * CAP * 4;                     // 12.8 MB
    unsigned short* Wt = (unsigned short*)p;                                 // 0.39 MB

    (void)hipMemsetAsync(cnt1, 0, (size_t)2 * N_NODES * 4, stream);

    prep_kernel<<<PREP_BLOCKS, 256, 0, stream>>>(
        x, xb, Ws, W1, W2, Wt, src1, dst1, src2, dst2, cnt1, cnt2, bkt1, bkt2);

    // Fused gather + MFMA GEMM + bias + relu
    gemm_kernel<<<(N_NODES + BM - 1) / BM, 512, 0, stream>>>(
        xb, cnt1, cnt2, bkt1, bkt2, Wt, bias, out);
}

// Round 8
// 393.591 us; speedup vs baseline: 1.2220x; 1.2220x over previous
//
#include <hip/hip_runtime.h>

#define N_NODES 100000
#define N_EDGES 500000
#define D 256
#define CAP 32          // bucket capacity per (node, relation); λ=5 ⇒ P(deg>32)≈1e-15
#define BM 128          // rows per gemm block

typedef __bf16 bf16x8 __attribute__((ext_vector_type(8)));
typedef float  f32x4  __attribute__((ext_vector_type(4)));
typedef unsigned int u32x2 __attribute__((ext_vector_type(2)));

// ---- bf16 helpers (manual, RNE) -------------------------------------------
__device__ __forceinline__ unsigned short f2bf(float f) {
    unsigned int u = __float_as_uint(f);
    u += 0x7fffu + ((u >> 16) & 1u);
    return (unsigned short)(u >> 16);
}
__device__ __forceinline__ float bf2f(unsigned short b) {
    return __uint_as_float(((unsigned int)b) << 16);
}

// ---- async global->LDS, 16B per lane (dest = uniform base + lane*16) ------
__device__ __forceinline__ void glds16(const unsigned short* g, unsigned short* l) {
    __builtin_amdgcn_global_load_lds(
        (const __attribute__((address_space(1))) unsigned int*)g,
        (__attribute__((address_space(3))) unsigned int*)l,
        16, 0, 0);
}

// ---------------------------------------------------------------------------
// Prep kernel, WAVE-granular role interleave (contiguous convert streams;
// Wt PRE-SWIZZLED k' = k ^ (((n>>1)&3)<<3) for linear-dest global_load_lds
// staging in the GEMM, m173 pattern).
// Of every 22 waves: 16 convert, 5 bucket, 1 W-prep.
// ---------------------------------------------------------------------------
#define PREP_BLOCKS 17188   // ceil(22*3125 waves / 4 per block)

__global__ __launch_bounds__(256) void prep_kernel(
    const float* __restrict__ x, unsigned short* __restrict__ xb,
    const float* __restrict__ Ws, const float* __restrict__ W1,
    const float* __restrict__ W2, unsigned short* __restrict__ Wt,
    const int* __restrict__ src1, const int* __restrict__ dst1,
    const int* __restrict__ src2, const int* __restrict__ dst2,
    int* __restrict__ cnt1, int* __restrict__ cnt2,
    int* __restrict__ bkt1, int* __restrict__ bkt2)
{
    const int wid  = blockIdx.x * 4 + (threadIdx.x >> 6);  // global wave id
    const int lane = threadIdx.x & 63;
    const int group = wid / 22;
    const int pos   = wid - group * 22;

    if (pos < 16) {
        // ---- convert role: x fp32 -> xb bf16, 8 elems/lane, contiguous ----
        int cw = group * 16 + pos;
        if (cw >= 50000) return;
        size_t base = (size_t)cw * 512;
        float4 a = *(const float4*)(x + base + lane * 4);
        float4 c = *(const float4*)(x + base + 256 + lane * 4);
        ushort4 oa, oc;
        oa.x = f2bf(a.x); oa.y = f2bf(a.y); oa.z = f2bf(a.z); oa.w = f2bf(a.w);
        oc.x = f2bf(c.x); oc.y = f2bf(c.y); oc.z = f2bf(c.z); oc.w = f2bf(c.w);
        *(ushort4*)(xb + base + lane * 4) = oa;
        *(ushort4*)(xb + base + 256 + lane * 4) = oc;
    } else if (pos < 21) {
        // ---- bucket role: 1 edge/lane, cnt/bkt atomics (L2-resident) ----
        int bw = group * 5 + (pos - 16);
        int e = bw * 64 + lane;
        if (e >= 2 * N_EDGES) return;
        bool r2 = (e >= N_EDGES);
        const int* src = r2 ? src2 : src1;
        const int* dst = r2 ? dst2 : dst1;
        int* cnt = r2 ? cnt2 : cnt1;
        int* bkt = r2 ? bkt2 : bkt1;
        int ei = r2 ? e - N_EDGES : e;
        int s = src[ei], d = dst[ei];
        int p = atomicAdd(&cnt[d], 1);
        if (p < CAP) bkt[d * CAP + p] = s;
    } else {
        // ---- W-prep role: Wt[n][k^swz] = bf16(scale_k * W[k%256][n]) ----
        int idx = group * 64 + lane;
        if (idx >= 3 * D * D) return;
        int k = idx >> 8;
        int n = idx & (D - 1);
        const float* W = (k < D) ? Ws : (k < 2 * D ? W1 : W2);
        float scale = (k < D) ? 1.1f : 1.0f;
        int dk = k ^ ((((n >> 1) & 3)) << 3);   // pre-swizzle 16B chunk slot
        Wt[(size_t)n * (3 * D) + dk] = f2bf(W[(size_t)(k & (D - 1)) * D + n] * scale);
    }
}

// ---------------------------------------------------------------------------
// Gather: one wave per (node, relation) — round-0 structure.
// 200K independent single-task waves = unbounded TLP; chunk-8 row preload
// (8 independent 512B reads in flight), wave-uniform predicated accumulate,
// rare tail loop, NON-TEMPORAL xa writes.
// Rounds 1-6 lesson: every in-GEMM fusion re-serializes this and loses more
// than the 102MB xa round trip costs. Keep it split.
// ---------------------------------------------------------------------------
__global__ __launch_bounds__(256) void gather_kernel(
    const unsigned short* __restrict__ xb,
    const int* __restrict__ cnt1, const int* __restrict__ cnt2,
    const int* __restrict__ bkt1, const int* __restrict__ bkt2,
    unsigned short* __restrict__ xa1, unsigned short* __restrict__ xa2)
{
    long long gid = (long long)blockIdx.x * blockDim.x + threadIdx.x;
    int w = (int)(gid >> 6);
    int lane = (int)(gid & 63);
    if (w >= 2 * N_NODES) return;
    int node = w >> 1;
    int rel  = w & 1;

    const int* cnt = rel ? cnt2 : cnt1;
    const int* bkt = rel ? bkt2 : bkt1;
    unsigned short* xa = rel ? xa2 : xa1;

    int c = cnt[node]; if (c > CAP) c = CAP;
    int sid = (lane < c) ? bkt[(size_t)node * CAP + lane] : 0;

    ushort4 v[8];
    #pragma unroll
    for (int t = 0; t < 8; ++t) {
        int s = __shfl(sid, t);
        v[t] = *(const ushort4*)(xb + (size_t)s * D + lane * 4);
    }

    float a0 = 0.f, a1 = 0.f, a2 = 0.f, a3 = 0.f;
    #pragma unroll
    for (int t = 0; t < 8; ++t) {
        if (t < c) {   // wave-uniform predicate (scalar branch)
            a0 += bf2f(v[t].x); a1 += bf2f(v[t].y);
            a2 += bf2f(v[t].z); a3 += bf2f(v[t].w);
        }
    }
    for (int e = 8; e < c; ++e) {
        int s = __shfl(sid, e);
        ushort4 t = *(const ushort4*)(xb + (size_t)s * D + lane * 4);
        a0 += bf2f(t.x); a1 += bf2f(t.y); a2 += bf2f(t.z); a3 += bf2f(t.w);
    }

    u32x2 o;
    o.x = (unsigned)f2bf(a0) | ((unsigned)f2bf(a1) << 16);
    o.y = (unsigned)f2bf(a2) | ((unsigned)f2bf(a3) << 16);
    __builtin_nontemporal_store(o, (u32x2*)(xa + (size_t)node * D + lane * 4));
}

// ---------------------------------------------------------------------------
// MFMA GEMM: out = relu([xb|xa1|xa2] @ Wt^T + bias).
// m97-shape: ALL staging via width-16 global_load_lds (A: source-side
// chunk-XOR on per-lane address; B: from pre-swizzled Wt — both patterns
// correctness-proven in round 6), double-buffered LDS (48KB), ONE barrier
// per K-iteration (stage kt+1 -> MFMA kt -> barrier). Zero staging
// registers / ds_writes: ~95 unified regs -> (512,4) 2 blocks/CU, no spill.
// ---------------------------------------------------------------------------
__global__ __launch_bounds__(512, 4) void gemm_kernel(
    const unsigned short* __restrict__ xb,
    const unsigned short* __restrict__ xa1,
    const unsigned short* __restrict__ xa2,
    const unsigned short* __restrict__ Wt,   // [256 n][768 k] bf16, PRE-SWIZZLED
    const float* __restrict__ bias, float* __restrict__ out)
{
    __shared__ unsigned short Alds[2][BM * 32];     // 2 x 8 KB
    __shared__ unsigned short Blds[2][256 * 32];    // 2 x 16 KB

    const int tid  = threadIdx.x;
    const int lane = tid & 63;
    const int wave = tid >> 6;          // 0..7
    const int quad = lane >> 4;
    const int l15  = lane & 15;
    const int m0 = blockIdx.x * BM;
    const int wm = (wave >> 2) * 64;    // 2 m-waves x 4 n-waves of 64
    const int wn = (wave & 3) * 64;
    const int swz = (l15 >> 1) & 3;     // read-side chunk swizzle (row>>1)&3

    // glds geometry: each wave stages a 16-row slab; lane -> (row, chunk).
    const int gr   = lane >> 2;                 // row within slab 0..15
    const int gch  = lane & 3;                  // chunk slot 0..3
    const int gswz = (lane >> 3) & 3;           // (row>>1)&3 within slab
    int mRow = m0 + (wave << 4) + gr;           // A row this lane stages
    if (mRow >= N_NODES) mRow = N_NODES - 1;
    const size_t aRowOff = (size_t)mRow * D + ((gch ^ gswz) << 3);  // src XOR
    const unsigned short* bSrc0 = Wt + (size_t)((wave << 4) + gr) * (3 * D) + (gch << 3);
    const unsigned short* bSrc1 = bSrc0 + (size_t)128 * (3 * D);
    const unsigned short* Aseg[3] = {xb, xa1, xa2};

    f32x4 acc[4][4] = {};

    // Prologue: stage tile 0 into buffer 0.
    glds16(Aseg[0] + aRowOff, &Alds[0][wave * 512]);
    glds16(bSrc0, &Blds[0][wave * 512]);
    glds16(bSrc1, &Blds[0][4096 + wave * 512]);
    __syncthreads();

    for (int kt = 0; kt < 24; ++kt) {
        const int ktn = kt + 1;
        if (ktn < 24) {   // stage next tile into the other buffer (async)
            glds16(Aseg[ktn >> 3] + aRowOff + ((ktn & 7) * 32), &Alds[ktn & 1][wave * 512]);
            glds16(bSrc0 + ktn * 32, &Blds[ktn & 1][wave * 512]);
            glds16(bSrc1 + ktn * 32, &Blds[ktn & 1][4096 + wave * 512]);
        }

        // MFMA on current buffer (B frags held across i)
        const unsigned short* Ab = &Alds[kt & 1][0];
        const unsigned short* Bb = &Blds[kt & 1][0];
        bf16x8 b0f = *(const bf16x8*)(Bb + (wn +  0 + l15) * 32 + ((quad ^ swz) * 8));
        bf16x8 b1f = *(const bf16x8*)(Bb + (wn + 16 + l15) * 32 + ((quad ^ swz) * 8));
        bf16x8 b2f = *(const bf16x8*)(Bb + (wn + 32 + l15) * 32 + ((quad ^ swz) * 8));
        bf16x8 b3f = *(const bf16x8*)(Bb + (wn + 48 + l15) * 32 + ((quad ^ swz) * 8));
        #pragma unroll
        for (int i = 0; i < 4; ++i) {
            bf16x8 afi = *(const bf16x8*)(Ab + (wm + i * 16 + l15) * 32 + ((quad ^ swz) * 8));
            acc[i][0] = __builtin_amdgcn_mfma_f32_16x16x32_bf16(afi, b0f, acc[i][0], 0, 0, 0);
            acc[i][1] = __builtin_amdgcn_mfma_f32_16x16x32_bf16(afi, b1f, acc[i][1], 0, 0, 0);
            acc[i][2] = __builtin_amdgcn_mfma_f32_16x16x32_bf16(afi, b2f, acc[i][2], 0, 0, 0);
            acc[i][3] = __builtin_amdgcn_mfma_f32_16x16x32_bf16(afi, b3f, acc[i][3], 0, 0, 0);
        }
        __syncthreads();   // one barrier/iter: next buffer staged + this one free
    }

    // Epilogue: D layout col=lane&15, row=quad*4+reg (m89/m91 verified).
    #pragma unroll
    for (int j = 0; j < 4; ++j) {
        int col = wn + j * 16 + l15;
        float bj = bias[col];
        #pragma unroll
        for (int i = 0; i < 4; ++i) {
            int rb = m0 + wm + i * 16 + quad * 4;
            #pragma unroll
            for (int r = 0; r < 4; ++r) {
                int m = rb + r;
                if (m < N_NODES)
                    __builtin_nontemporal_store(
                        fmaxf(acc[i][j][r] + bj, 0.f),
                        out + (size_t)m * D + col);
            }
        }
    }
}

extern "C" void kernel_launch(void* const* d_in, const int* in_sizes, int n_in,
                              void* d_out, int out_size, void* d_ws, size_t ws_size,
                              hipStream_t stream) {
    const float* x    = (const float*)d_in[0];
    const float* Ws   = (const float*)d_in[1];
    const float* W1   = (const float*)d_in[2];
    const float* W2   = (const float*)d_in[3];
    const float* bias = (const float*)d_in[4];
    const int* src1   = (const int*)d_in[5];
    const int* dst1   = (const int*)d_in[6];
    const int* src2   = (const int*)d_in[7];
    const int* dst2   = (const int*)d_in[8];
    float* out = (float*)d_out;

    // Workspace layout (total 180.4 MB):
    char* p = (char*)d_ws;
    unsigned short* xb  = (unsigned short*)p; p += (size_t)N_NODES * D * 2;  // 51.2 MB
    unsigned short* xa1 = (unsigned short*)p; p += (size_t)N_NODES * D * 2;  // 51.2 MB
    unsigned short* xa2 = (unsigned short*)p; p += (size_t)N_NODES * D * 2;  // 51.2 MB
    int* cnt1 = (int*)p; p += (size_t)N_NODES * 4;                           // 0.4 MB
    int* cnt2 = (int*)p; p += (size_t)N_NODES * 4;                           // 0.4 MB
    int* bkt1 = (int*)p; p += (size_t)N_NODES * CAP * 4;                     // 12.8 MB
    int* bkt2 = (int*)p; p += (size_t)N_NODES * CAP * 4;                     // 12.8 MB
    unsigned short* Wt = (unsigned short*)p;                                 // 0.39 MB

    (void)hipMemsetAsync(cnt1, 0, (size_t)2 * N_NODES * 4, stream);

    prep_kernel<<<PREP_BLOCKS, 256, 0, stream>>>(
        x, xb, Ws, W1, W2, Wt, src1, dst1, src2, dst2, cnt1, cnt2, bkt1, bkt2);

    {   // gather-aggregate, one wave per (node, relation)
        long long total = (long long)2 * N_NODES * 64;
        gather_kernel<<<(int)((total + 255) / 256), 256, 0, stream>>>(
            xb, cnt1, cnt2, bkt1, bkt2, xa1, xa2);
    }
    {   // MFMA GEMM + bias + relu, full-N blocks
        gemm_kernel<<<(N_NODES + BM - 1) / BM, 512, 0, stream>>>(
            xb, xa1, xa2, Wt, bias, out);
    }
}

// Round 9
// 385.874 us; speedup vs baseline: 1.2465x; 1.0200x over previous
//
#include <hip/hip_runtime.h>

#define N_NODES 100000
#define N_EDGES 500000
#define D 256
#define CAP 32          // bucket capacity per (node, relation); λ=5 ⇒ P(deg>32)≈1e-15
#define BM 128          // rows per gemm block

typedef __bf16 bf16x8 __attribute__((ext_vector_type(8)));
typedef float  f32x4  __attribute__((ext_vector_type(4)));
typedef unsigned int u32x2 __attribute__((ext_vector_type(2)));

// ---- bf16 helpers (manual, RNE) -------------------------------------------
__device__ __forceinline__ unsigned short f2bf(float f) {
    unsigned int u = __float_as_uint(f);
    u += 0x7fffu + ((u >> 16) & 1u);
    return (unsigned short)(u >> 16);
}
__device__ __forceinline__ float bf2f(unsigned short b) {
    return __uint_as_float(((unsigned int)b) << 16);
}

// ---- async global->LDS, 16B per lane (dest = uniform base + lane*16) ------
__device__ __forceinline__ void glds16(const unsigned short* g, unsigned short* l) {
    __builtin_amdgcn_global_load_lds(
        (const __attribute__((address_space(1))) unsigned int*)g,
        (__attribute__((address_space(3))) unsigned int*)l,
        16, 0, 0);
}

// ---------------------------------------------------------------------------
// Prep kernel, WAVE-granular role interleave (unchanged from round 8).
// Wt PRE-SWIZZLED k' = k ^ (((n>>1)&3)<<3) for linear-dest global_load_lds
// staging in the GEMM (m173 pattern).
// Of every 22 waves: 16 convert, 5 bucket, 1 W-prep.
// ---------------------------------------------------------------------------
#define PREP_BLOCKS 17188   // ceil(22*3125 waves / 4 per block)

__global__ __launch_bounds__(256) void prep_kernel(
    const float* __restrict__ x, unsigned short* __restrict__ xb,
    const float* __restrict__ Ws, const float* __restrict__ W1,
    const float* __restrict__ W2, unsigned short* __restrict__ Wt,
    const int* __restrict__ src1, const int* __restrict__ dst1,
    const int* __restrict__ src2, const int* __restrict__ dst2,
    int* __restrict__ cnt1, int* __restrict__ cnt2,
    int* __restrict__ bkt1, int* __restrict__ bkt2)
{
    const int wid  = blockIdx.x * 4 + (threadIdx.x >> 6);  // global wave id
    const int lane = threadIdx.x & 63;
    const int group = wid / 22;
    const int pos   = wid - group * 22;

    if (pos < 16) {
        // ---- convert role: x fp32 -> xb bf16, 8 elems/lane, contiguous ----
        int cw = group * 16 + pos;
        if (cw >= 50000) return;
        size_t base = (size_t)cw * 512;
        float4 a = *(const float4*)(x + base + lane * 4);
        float4 c = *(const float4*)(x + base + 256 + lane * 4);
        ushort4 oa, oc;
        oa.x = f2bf(a.x); oa.y = f2bf(a.y); oa.z = f2bf(a.z); oa.w = f2bf(a.w);
        oc.x = f2bf(c.x); oc.y = f2bf(c.y); oc.z = f2bf(c.z); oc.w = f2bf(c.w);
        *(ushort4*)(xb + base + lane * 4) = oa;
        *(ushort4*)(xb + base + 256 + lane * 4) = oc;
    } else if (pos < 21) {
        // ---- bucket role: 1 edge/lane, cnt/bkt atomics (L2-resident) ----
        int bw = group * 5 + (pos - 16);
        int e = bw * 64 + lane;
        if (e >= 2 * N_EDGES) return;
        bool r2 = (e >= N_EDGES);
        const int* src = r2 ? src2 : src1;
        const int* dst = r2 ? dst2 : dst1;
        int* cnt = r2 ? cnt2 : cnt1;
        int* bkt = r2 ? bkt2 : bkt1;
        int ei = r2 ? e - N_EDGES : e;
        int s = src[ei], d = dst[ei];
        int p = atomicAdd(&cnt[d], 1);
        if (p < CAP) bkt[d * CAP + p] = s;
    } else {
        // ---- W-prep role: Wt[n][k^swz] = bf16(scale_k * W[k%256][n]) ----
        int idx = group * 64 + lane;
        if (idx >= 3 * D * D) return;
        int k = idx >> 8;
        int n = idx & (D - 1);
        const float* W = (k < D) ? Ws : (k < 2 * D ? W1 : W2);
        float scale = (k < D) ? 1.1f : 1.0f;
        int dk = k ^ ((((n >> 1) & 3)) << 3);   // pre-swizzle 16B chunk slot
        Wt[(size_t)n * (3 * D) + dk] = f2bf(W[(size_t)(k & (D - 1)) * D + n] * scale);
    }
}

// ---------------------------------------------------------------------------
// Gather, round-9: one wave per NODE, BOTH relations per task.
// Round-8 profile: gather is the top kernel (100us); VALUBusy 42%, HBM 44%
// — neither pipe saturated => dependency-chain (ILP) limited: each wave did
// load-8 -> drain -> fold -> store -> exit. Fix: issue BOTH relations' 8-row
// batches back-to-back (16 independent 512B loads, 8KB in flight). In-order
// vmcnt means fold-rel1 only waits on the first 8; rel2's loads stay in
// flight under rel1's ~64 VALU fold + NT store. Halves per-task overhead.
// ---------------------------------------------------------------------------
__global__ __launch_bounds__(256) void gather_kernel(
    const unsigned short* __restrict__ xb,
    const int* __restrict__ cnt1, const int* __restrict__ cnt2,
    const int* __restrict__ bkt1, const int* __restrict__ bkt2,
    unsigned short* __restrict__ xa1, unsigned short* __restrict__ xa2)
{
    long long gid = (long long)blockIdx.x * blockDim.x + threadIdx.x;
    int node = (int)(gid >> 6);
    int lane = (int)(gid & 63);
    if (node >= N_NODES) return;

    int c1 = cnt1[node]; if (c1 > CAP) c1 = CAP;
    int c2 = cnt2[node]; if (c2 > CAP) c2 = CAP;
    int sid1 = (lane < c1) ? bkt1[(size_t)node * CAP + lane] : 0;
    int sid2 = (lane < c2) ? bkt2[(size_t)node * CAP + lane] : 0;

    // 16 independent 512B row reads in flight (rel1 first, rel2 behind it).
    ushort4 v1[8], v2[8];
    #pragma unroll
    for (int t = 0; t < 8; ++t)
        v1[t] = *(const ushort4*)(xb + (size_t)__shfl(sid1, t) * D + lane * 4);
    #pragma unroll
    for (int t = 0; t < 8; ++t)
        v2[t] = *(const ushort4*)(xb + (size_t)__shfl(sid2, t) * D + lane * 4);

    // ---- rel1 fold (waits only on v1's 8 loads; v2 still in flight) ----
    {
        float a0 = 0.f, a1 = 0.f, a2 = 0.f, a3 = 0.f;
        #pragma unroll
        for (int t = 0; t < 8; ++t)
            if (t < c1) {   // wave-uniform predicate
                a0 += bf2f(v1[t].x); a1 += bf2f(v1[t].y);
                a2 += bf2f(v1[t].z); a3 += bf2f(v1[t].w);
            }
        for (int e = 8; e < c1; ++e) {   // tail P(deg>8)≈7%
            int s = __shfl(sid1, e);
            ushort4 t = *(const ushort4*)(xb + (size_t)s * D + lane * 4);
            a0 += bf2f(t.x); a1 += bf2f(t.y); a2 += bf2f(t.z); a3 += bf2f(t.w);
        }
        u32x2 o;
        o.x = (unsigned)f2bf(a0) | ((unsigned)f2bf(a1) << 16);
        o.y = (unsigned)f2bf(a2) | ((unsigned)f2bf(a3) << 16);
        __builtin_nontemporal_store(o, (u32x2*)(xa1 + (size_t)node * D + lane * 4));
    }

    // ---- rel2 fold ----
    {
        float a0 = 0.f, a1 = 0.f, a2 = 0.f, a3 = 0.f;
        #pragma unroll
        for (int t = 0; t < 8; ++t)
            if (t < c2) {
                a0 += bf2f(v2[t].x); a1 += bf2f(v2[t].y);
                a2 += bf2f(v2[t].z); a3 += bf2f(v2[t].w);
            }
        for (int e = 8; e < c2; ++e) {
            int s = __shfl(sid2, e);
            ushort4 t = *(const ushort4*)(xb + (size_t)s * D + lane * 4);
            a0 += bf2f(t.x); a1 += bf2f(t.y); a2 += bf2f(t.z); a3 += bf2f(t.w);
        }
        u32x2 o;
        o.x = (unsigned)f2bf(a0) | ((unsigned)f2bf(a1) << 16);
        o.y = (unsigned)f2bf(a2) | ((unsigned)f2bf(a3) << 16);
        __builtin_nontemporal_store(o, (u32x2*)(xa2 + (size_t)node * D + lane * 4));
    }
}

// ---------------------------------------------------------------------------
// MFMA GEMM (unchanged from round 8): out = relu([xb|xa1|xa2] @ Wt^T + bias).
// All staging via width-16 global_load_lds (A: source-side chunk-XOR; B:
// pre-swizzled Wt), double-buffered LDS (48KB), ONE barrier per K-iteration.
// ---------------------------------------------------------------------------
__global__ __launch_bounds__(512, 4) void gemm_kernel(
    const unsigned short* __restrict__ xb,
    const unsigned short* __restrict__ xa1,
    const unsigned short* __restrict__ xa2,
    const unsigned short* __restrict__ Wt,   // [256 n][768 k] bf16, PRE-SWIZZLED
    const float* __restrict__ bias, float* __restrict__ out)
{
    __shared__ unsigned short Alds[2][BM * 32];     // 2 x 8 KB
    __shared__ unsigned short Blds[2][256 * 32];    // 2 x 16 KB

    const int tid  = threadIdx.x;
    const int lane = tid & 63;
    const int wave = tid >> 6;          // 0..7
    const int quad = lane >> 4;
    const int l15  = lane & 15;
    const int m0 = blockIdx.x * BM;
    const int wm = (wave >> 2) * 64;    // 2 m-waves x 4 n-waves of 64
    const int wn = (wave & 3) * 64;
    const int swz = (l15 >> 1) & 3;     // read-side chunk swizzle (row>>1)&3

    // glds geometry: each wave stages a 16-row slab; lane -> (row, chunk).
    const int gr   = lane >> 2;                 // row within slab 0..15
    const int gch  = lane & 3;                  // chunk slot 0..3
    const int gswz = (lane >> 3) & 3;           // (row>>1)&3 within slab
    int mRow = m0 + (wave << 4) + gr;           // A row this lane stages
    if (mRow >= N_NODES) mRow = N_NODES - 1;
    const size_t aRowOff = (size_t)mRow * D + ((gch ^ gswz) << 3);  // src XOR
    const unsigned short* bSrc0 = Wt + (size_t)((wave << 4) + gr) * (3 * D) + (gch << 3);
    const unsigned short* bSrc1 = bSrc0 + (size_t)128 * (3 * D);
    const unsigned short* Aseg[3] = {xb, xa1, xa2};

    f32x4 acc[4][4] = {};

    // Prologue: stage tile 0 into buffer 0.
    glds16(Aseg[0] + aRowOff, &Alds[0][wave * 512]);
    glds16(bSrc0, &Blds[0][wave * 512]);
    glds16(bSrc1, &Blds[0][4096 + wave * 512]);
    __syncthreads();

    for (int kt = 0; kt < 24; ++kt) {
        const int ktn = kt + 1;
        if (ktn < 24) {   // stage next tile into the other buffer (async)
            glds16(Aseg[ktn >> 3] + aRowOff + ((ktn & 7) * 32), &Alds[ktn & 1][wave * 512]);
            glds16(bSrc0 + ktn * 32, &Blds[ktn & 1][wave * 512]);
            glds16(bSrc1 + ktn * 32, &Blds[ktn & 1][4096 + wave * 512]);
        }

        // MFMA on current buffer (B frags held across i)
        const unsigned short* Ab = &Alds[kt & 1][0];
        const unsigned short* Bb = &Blds[kt & 1][0];
        bf16x8 b0f = *(const bf16x8*)(Bb + (wn +  0 + l15) * 32 + ((quad ^ swz) * 8));
        bf16x8 b1f = *(const bf16x8*)(Bb + (wn + 16 + l15) * 32 + ((quad ^ swz) * 8));
        bf16x8 b2f = *(const bf16x8*)(Bb + (wn + 32 + l15) * 32 + ((quad ^ swz) * 8));
        bf16x8 b3f = *(const bf16x8*)(Bb + (wn + 48 + l15) * 32 + ((quad ^ swz) * 8));
        #pragma unroll
        for (int i = 0; i < 4; ++i) {
            bf16x8 afi = *(const bf16x8*)(Ab + (wm + i * 16 + l15) * 32 + ((quad ^ swz) * 8));
            acc[i][0] = __builtin_amdgcn_mfma_f32_16x16x32_bf16(afi, b0f, acc[i][0], 0, 0, 0);
            acc[i][1] = __builtin_amdgcn_mfma_f32_16x16x32_bf16(afi, b1f, acc[i][1], 0, 0, 0);
            acc[i][2] = __builtin_amdgcn_mfma_f32_16x16x32_bf16(afi, b2f, acc[i][2], 0, 0, 0);
            acc[i][3] = __builtin_amdgcn_mfma_f32_16x16x32_bf16(afi, b3f, acc[i][3], 0, 0, 0);
        }
        __syncthreads();   // one barrier/iter: next buffer staged + this one free
    }

    // Epilogue: D layout col=lane&15, row=quad*4+reg (m89/m91 verified).
    #pragma unroll
    for (int j = 0; j < 4; ++j) {
        int col = wn + j * 16 + l15;
        float bj = bias[col];
        #pragma unroll
        for (int i = 0; i < 4; ++i) {
            int rb = m0 + wm + i * 16 + quad * 4;
            #pragma unroll
            for (int r = 0; r < 4; ++r) {
                int m = rb + r;
                if (m < N_NODES)
                    __builtin_nontemporal_store(
                        fmaxf(acc[i][j][r] + bj, 0.f),
                        out + (size_t)m * D + col);
            }
        }
    }
}

extern "C" void kernel_launch(void* const* d_in, const int* in_sizes, int n_in,
                              void* d_out, int out_size, void* d_ws, size_t ws_size,
                              hipStream_t stream) {
    const float* x    = (const float*)d_in[0];
    const float* Ws   = (const float*)d_in[1];
    const float* W1   = (const float*)d_in[2];
    const float* W2   = (const float*)d_in[3];
    const float* bias = (const float*)d_in[4];
    const int* src1   = (const int*)d_in[5];
    const int* dst1   = (const int*)d_in[6];
    const int* src2   = (const int*)d_in[7];
    const int* dst2   = (const int*)d_in[8];
    float* out = (float*)d_out;

    // Workspace layout (total 180.4 MB):
    char* p = (char*)d_ws;
    unsigned short* xb  = (unsigned short*)p; p += (size_t)N_NODES * D * 2;  // 51.2 MB
    unsigned short* xa1 = (unsigned short*)p; p += (size_t)N_NODES * D * 2;  // 51.2 MB
    unsigned short* xa2 = (unsigned short*)p; p += (size_t)N_NODES * D * 2;  // 51.2 MB
    int* cnt1 = (int*)p; p += (size_t)N_NODES * 4;                           // 0.4 MB
    int* cnt2 = (int*)p; p += (size_t)N_NODES * 4;                           // 0.4 MB
    int* bkt1 = (int*)p; p += (size_t)N_NODES * CAP * 4;                     // 12.8 MB
    int* bkt2 = (int*)p; p += (size_t)N_NODES * CAP * 4;                     // 12.8 MB
    unsigned short* Wt = (unsigned short*)p;                                 // 0.39 MB

    (void)hipMemsetAsync(cnt1, 0, (size_t)2 * N_NODES * 4, stream);

    prep_kernel<<<PREP_BLOCKS, 256, 0, stream>>>(
        x, xb, Ws, W1, W2, Wt, src1, dst1, src2, dst2, cnt1, cnt2, bkt1, bkt2);

    {   // gather-aggregate, one wave per node (both relations)
        long long total = (long long)N_NODES * 64;
        gather_kernel<<<(int)((total + 255) / 256), 256, 0, stream>>>(
            xb, cnt1, cnt2, bkt1, bkt2, xa1, xa2);
    }
    {   // MFMA GEMM + bias + relu, full-N blocks
        gemm_kernel<<<(N_NODES + BM - 1) / BM, 512, 0, stream>>>(
            xb, xa1, xa2, Wt, bias, out);
    }
}

// Round 10
// 376.843 us; speedup vs baseline: 1.2763x; 1.0240x over previous
//
#include <hip/hip_runtime.h>

#define N_NODES 100000
#define N_EDGES 500000
#define D 256
#define CAP 32          // bucket capacity per (node, relation); λ=5 ⇒ P(deg>32)≈1e-15
#define BM 128          // rows per gemm block

typedef __bf16 bf16x8 __attribute__((ext_vector_type(8)));
typedef float  f32x4  __attribute__((ext_vector_type(4)));
typedef unsigned int u32x2 __attribute__((ext_vector_type(2)));

// ---- bf16 helpers (manual, RNE) -------------------------------------------
__device__ __forceinline__ unsigned short f2bf(float f) {
    unsigned int u = __float_as_uint(f);
    u += 0x7fffu + ((u >> 16) & 1u);
    return (unsigned short)(u >> 16);
}
__device__ __forceinline__ float bf2f(unsigned short b) {
    return __uint_as_float(((unsigned int)b) << 16);
}

// ---- async global->LDS, 16B per lane (dest = uniform base + lane*16) ------
__device__ __forceinline__ void glds16(const unsigned short* g, unsigned short* l) {
    __builtin_amdgcn_global_load_lds(
        (const __attribute__((address_space(1))) unsigned int*)g,
        (__attribute__((address_space(3))) unsigned int*)l,
        16, 0, 0);
}

// ---------------------------------------------------------------------------
// Prep kernel, WAVE-granular role interleave (unchanged).
// Wt PRE-SWIZZLED k' = k ^ (((n>>1)&3)<<3) for linear-dest global_load_lds
// staging in the GEMM (m173 pattern).
// ---------------------------------------------------------------------------
#define PREP_BLOCKS 17188   // ceil(22*3125 waves / 4 per block)

__global__ __launch_bounds__(256) void prep_kernel(
    const float* __restrict__ x, unsigned short* __restrict__ xb,
    const float* __restrict__ Ws, const float* __restrict__ W1,
    const float* __restrict__ W2, unsigned short* __restrict__ Wt,
    const int* __restrict__ src1, const int* __restrict__ dst1,
    const int* __restrict__ src2, const int* __restrict__ dst2,
    int* __restrict__ cnt1, int* __restrict__ cnt2,
    int* __restrict__ bkt1, int* __restrict__ bkt2)
{
    const int wid  = blockIdx.x * 4 + (threadIdx.x >> 6);  // global wave id
    const int lane = threadIdx.x & 63;
    const int group = wid / 22;
    const int pos   = wid - group * 22;

    if (pos < 16) {
        // ---- convert role: x fp32 -> xb bf16, 8 elems/lane, contiguous ----
        int cw = group * 16 + pos;
        if (cw >= 50000) return;
        size_t base = (size_t)cw * 512;
        float4 a = *(const float4*)(x + base + lane * 4);
        float4 c = *(const float4*)(x + base + 256 + lane * 4);
        ushort4 oa, oc;
        oa.x = f2bf(a.x); oa.y = f2bf(a.y); oa.z = f2bf(a.z); oa.w = f2bf(a.w);
        oc.x = f2bf(c.x); oc.y = f2bf(c.y); oc.z = f2bf(c.z); oc.w = f2bf(c.w);
        *(ushort4*)(xb + base + lane * 4) = oa;
        *(ushort4*)(xb + base + 256 + lane * 4) = oc;
    } else if (pos < 21) {
        // ---- bucket role: 1 edge/lane, cnt/bkt atomics (L2-resident) ----
        int bw = group * 5 + (pos - 16);
        int e = bw * 64 + lane;
        if (e >= 2 * N_EDGES) return;
        bool r2 = (e >= N_EDGES);
        const int* src = r2 ? src2 : src1;
        const int* dst = r2 ? dst2 : dst1;
        int* cnt = r2 ? cnt2 : cnt1;
        int* bkt = r2 ? bkt2 : bkt1;
        int ei = r2 ? e - N_EDGES : e;
        int s = src[ei], d = dst[ei];
        int p = atomicAdd(&cnt[d], 1);
        if (p < CAP) bkt[d * CAP + p] = s;
    } else {
        // ---- W-prep role: Wt[n][k^swz] = bf16(scale_k * W[k%256][n]) ----
        int idx = group * 64 + lane;
        if (idx >= 3 * D * D) return;
        int k = idx >> 8;
        int n = idx & (D - 1);
        const float* W = (k < D) ? Ws : (k < 2 * D ? W1 : W2);
        float scale = (k < D) ? 1.1f : 1.0f;
        int dk = k ^ ((((n >> 1) & 3)) << 3);   // pre-swizzle 16B chunk slot
        Wt[(size_t)n * (3 * D) + dk] = f2bf(W[(size_t)(k & (D - 1)) * D + n] * scale);
    }
}

// ---------------------------------------------------------------------------
// Gather, one wave per NODE, both relations per task (round-9 structure).
// Round-10 change: xa stores are PLAIN (not nontemporal) — xa is consumed
// immediately by the GEMM; keeping it L2/L3-resident cuts gemm's HBM refetch
// (round-9 FETCH 78MB ≈ the NT-evicted xa). Near fabric roofline otherwise
// (~6.5 TB/s combined random-row read+write) — frozen.
// ---------------------------------------------------------------------------
__global__ __launch_bounds__(256) void gather_kernel(
    const unsigned short* __restrict__ xb,
    const int* __restrict__ cnt1, const int* __restrict__ cnt2,
    const int* __restrict__ bkt1, const int* __restrict__ bkt2,
    unsigned short* __restrict__ xa1, unsigned short* __restrict__ xa2)
{
    long long gid = (long long)blockIdx.x * blockDim.x + threadIdx.x;
    int node = (int)(gid >> 6);
    int lane = (int)(gid & 63);
    if (node >= N_NODES) return;

    int c1 = cnt1[node]; if (c1 > CAP) c1 = CAP;
    int c2 = cnt2[node]; if (c2 > CAP) c2 = CAP;
    int sid1 = (lane < c1) ? bkt1[(size_t)node * CAP + lane] : 0;
    int sid2 = (lane < c2) ? bkt2[(size_t)node * CAP + lane] : 0;

    // 16 independent 512B row reads in flight (rel1 first, rel2 behind it).
    ushort4 v1[8], v2[8];
    #pragma unroll
    for (int t = 0; t < 8; ++t)
        v1[t] = *(const ushort4*)(xb + (size_t)__shfl(sid1, t) * D + lane * 4);
    #pragma unroll
    for (int t = 0; t < 8; ++t)
        v2[t] = *(const ushort4*)(xb + (size_t)__shfl(sid2, t) * D + lane * 4);

    // ---- rel1 fold (waits only on v1's 8 loads; v2 still in flight) ----
    {
        float a0 = 0.f, a1 = 0.f, a2 = 0.f, a3 = 0.f;
        #pragma unroll
        for (int t = 0; t < 8; ++t)
            if (t < c1) {   // wave-uniform predicate
                a0 += bf2f(v1[t].x); a1 += bf2f(v1[t].y);
                a2 += bf2f(v1[t].z); a3 += bf2f(v1[t].w);
            }
        for (int e = 8; e < c1; ++e) {   // tail P(deg>8)≈7%
            int s = __shfl(sid1, e);
            ushort4 t = *(const ushort4*)(xb + (size_t)s * D + lane * 4);
            a0 += bf2f(t.x); a1 += bf2f(t.y); a2 += bf2f(t.z); a3 += bf2f(t.w);
        }
        u32x2 o;
        o.x = (unsigned)f2bf(a0) | ((unsigned)f2bf(a1) << 16);
        o.y = (unsigned)f2bf(a2) | ((unsigned)f2bf(a3) << 16);
        *(u32x2*)(xa1 + (size_t)node * D + lane * 4) = o;
    }

    // ---- rel2 fold ----
    {
        float a0 = 0.f, a1 = 0.f, a2 = 0.f, a3 = 0.f;
        #pragma unroll
        for (int t = 0; t < 8; ++t)
            if (t < c2) {
                a0 += bf2f(v2[t].x); a1 += bf2f(v2[t].y);
                a2 += bf2f(v2[t].z); a3 += bf2f(v2[t].w);
            }
        for (int e = 8; e < c2; ++e) {
            int s = __shfl(sid2, e);
            ushort4 t = *(const ushort4*)(xb + (size_t)s * D + lane * 4);
            a0 += bf2f(t.x); a1 += bf2f(t.y); a2 += bf2f(t.z); a3 += bf2f(t.w);
        }
        u32x2 o;
        o.x = (unsigned)f2bf(a0) | ((unsigned)f2bf(a1) << 16);
        o.y = (unsigned)f2bf(a2) | ((unsigned)f2bf(a3) << 16);
        *(u32x2*)(xa2 + (size_t)node * D + lane * 4) = o;
    }
}

// ---------------------------------------------------------------------------
// MFMA GEMM, round-10: COUNTED-VMCNT 3-DEEP PIPELINE (T3/T4).
// Round-9 post-mortem: __syncthreads() = s_waitcnt vmcnt(0) + s_barrier —
// it drained the SAME-iteration prefetch glds => full L2 latency exposed 24x
// per block (MfmaUtil 15.7%, dur 97us vs ~30us memory floor).
// Fix: 3 LDS buffers (72KB, still 2 blocks/CU); iteration kt issues tile
// kt+2, then waits vmcnt(6) (tile kt's 3 loads done; 6 stay IN FLIGHT across
// the barrier — never drain to 0 in the loop), raw s_barrier, MFMAs, raw
// s_barrier (read-done before overwrite; tile kt+2's buffer was last read
// at iter kt-1, protected by that iteration's trailing barrier).
// Tail peeled: vmcnt(3) at kt=22, vmcnt(0) at kt=23.
// ---------------------------------------------------------------------------
__global__ __launch_bounds__(512, 4) void gemm_kernel(
    const unsigned short* __restrict__ xb,
    const unsigned short* __restrict__ xa1,
    const unsigned short* __restrict__ xa2,
    const unsigned short* __restrict__ Wt,   // [256 n][768 k] bf16, PRE-SWIZZLED
    const float* __restrict__ bias, float* __restrict__ out)
{
    __shared__ unsigned short Alds[3][BM * 32];     // 3 x 8 KB
    __shared__ unsigned short Blds[3][256 * 32];    // 3 x 16 KB

    const int tid  = threadIdx.x;
    const int lane = tid & 63;
    const int wave = tid >> 6;          // 0..7
    const int quad = lane >> 4;
    const int l15  = lane & 15;
    const int m0 = blockIdx.x * BM;
    const int wm = (wave >> 2) * 64;    // 2 m-waves x 4 n-waves of 64
    const int wn = (wave & 3) * 64;
    const int swz = (l15 >> 1) & 3;     // read-side chunk swizzle (row>>1)&3

    // glds geometry: each wave stages a 16-row slab; lane -> (row, chunk).
    const int gr   = lane >> 2;                 // row within slab 0..15
    const int gch  = lane & 3;                  // chunk slot 0..3
    const int gswz = (lane >> 3) & 3;           // (row>>1)&3 within slab
    int mRow = m0 + (wave << 4) + gr;           // A row this lane stages
    if (mRow >= N_NODES) mRow = N_NODES - 1;
    const size_t aRowOff = (size_t)mRow * D + ((gch ^ gswz) << 3);  // src XOR
    const unsigned short* bSrc0 = Wt + (size_t)((wave << 4) + gr) * (3 * D) + (gch << 3);
    const unsigned short* bSrc1 = bSrc0 + (size_t)128 * (3 * D);
    const unsigned short* Aseg[3] = {xb, xa1, xa2};

    f32x4 acc[4][4] = {};

    // Prologue: issue tiles 0 and 1 (6 loads in flight; no barrier yet —
    // iteration 0's vmcnt(6)+barrier covers the first consume).
    glds16(Aseg[0] + aRowOff,            &Alds[0][wave * 512]);
    glds16(bSrc0,                        &Blds[0][wave * 512]);
    glds16(bSrc1,                        &Blds[0][4096 + wave * 512]);
    glds16(Aseg[0] + aRowOff + 32,       &Alds[1][wave * 512]);
    glds16(bSrc0 + 32,                   &Blds[1][wave * 512]);
    glds16(bSrc1 + 32,                   &Blds[1][4096 + wave * 512]);

    for (int kt = 0; kt < 24; ++kt) {
        const int kpre = kt + 2;
        if (kpre < 24) {   // issue tile kt+2 (buffer (kt+2)%3 — last read at kt-1)
            const int b = kpre % 3;
            glds16(Aseg[kpre >> 3] + aRowOff + ((kpre & 7) * 32), &Alds[b][wave * 512]);
            glds16(bSrc0 + kpre * 32, &Blds[b][wave * 512]);
            glds16(bSrc1 + kpre * 32, &Blds[b][4096 + wave * 512]);
        }

        // Counted wait: my 3 loads for tile kt retired; rest stay in flight.
        if (kt < 22)       asm volatile("s_waitcnt vmcnt(6)" ::: "memory");
        else if (kt == 22) asm volatile("s_waitcnt vmcnt(3)" ::: "memory");
        else               asm volatile("s_waitcnt vmcnt(0)" ::: "memory");
        __builtin_amdgcn_s_barrier();      // all waves' tile-kt loads landed
        asm volatile("" ::: "memory");

        // MFMA on buffer kt%3 (B frags held across i)
        const unsigned short* Ab = &Alds[kt % 3][0];
        const unsigned short* Bb = &Blds[kt % 3][0];
        bf16x8 b0f = *(const bf16x8*)(Bb + (wn +  0 + l15) * 32 + ((quad ^ swz) * 8));
        bf16x8 b1f = *(const bf16x8*)(Bb + (wn + 16 + l15) * 32 + ((quad ^ swz) * 8));
        bf16x8 b2f = *(const bf16x8*)(Bb + (wn + 32 + l15) * 32 + ((quad ^ swz) * 8));
        bf16x8 b3f = *(const bf16x8*)(Bb + (wn + 48 + l15) * 32 + ((quad ^ swz) * 8));
        #pragma unroll
        for (int i = 0; i < 4; ++i) {
            bf16x8 afi = *(const bf16x8*)(Ab + (wm + i * 16 + l15) * 32 + ((quad ^ swz) * 8));
            acc[i][0] = __builtin_amdgcn_mfma_f32_16x16x32_bf16(afi, b0f, acc[i][0], 0, 0, 0);
            acc[i][1] = __builtin_amdgcn_mfma_f32_16x16x32_bf16(afi, b1f, acc[i][1], 0, 0, 0);
            acc[i][2] = __builtin_amdgcn_mfma_f32_16x16x32_bf16(afi, b2f, acc[i][2], 0, 0, 0);
            acc[i][3] = __builtin_amdgcn_mfma_f32_16x16x32_bf16(afi, b3f, acc[i][3], 0, 0, 0);
        }

        asm volatile("" ::: "memory");
        __builtin_amdgcn_s_barrier();      // all waves done reading buffer kt%3
        asm volatile("" ::: "memory");
    }

    // Epilogue: D layout col=lane&15, row=quad*4+reg (m89/m91 verified).
    #pragma unroll
    for (int j = 0; j < 4; ++j) {
        int col = wn + j * 16 + l15;
        float bj = bias[col];
        #pragma unroll
        for (int i = 0; i < 4; ++i) {
            int rb = m0 + wm + i * 16 + quad * 4;
            #pragma unroll
            for (int r = 0; r < 4; ++r) {
                int m = rb + r;
                if (m < N_NODES)
                    __builtin_nontemporal_store(
                        fmaxf(acc[i][j][r] + bj, 0.f),
                        out + (size_t)m * D + col);
            }
        }
    }
}

extern "C" void kernel_launch(void* const* d_in, const int* in_sizes, int n_in,
                              void* d_out, int out_size, void* d_ws, size_t ws_size,
                              hipStream_t stream) {
    const float* x    = (const float*)d_in[0];
    const float* Ws   = (const float*)d_in[1];
    const float* W1   = (const float*)d_in[2];
    const float* W2   = (const float*)d_in[3];
    const float* bias = (const float*)d_in[4];
    const int* src1   = (const int*)d_in[5];
    const int* dst1   = (const int*)d_in[6];
    const int* src2   = (const int*)d_in[7];
    const int* dst2   = (const int*)d_in[8];
    float* out = (float*)d_out;

    // Workspace layout (total 180.4 MB):
    char* p = (char*)d_ws;
    unsigned short* xb  = (unsigned short*)p; p += (size_t)N_NODES * D * 2;  // 51.2 MB
    unsigned short* xa1 = (unsigned short*)p; p += (size_t)N_NODES * D * 2;  // 51.2 MB
    unsigned short* xa2 = (unsigned short*)p; p += (size_t)N_NODES * D * 2;  // 51.2 MB
    int* cnt1 = (int*)p; p += (size_t)N_NODES * 4;                           // 0.4 MB
    int* cnt2 = (int*)p; p += (size_t)N_NODES * 4;                           // 0.4 MB
    int* bkt1 = (int*)p; p += (size_t)N_NODES * CAP * 4;                     // 12.8 MB
    int* bkt2 = (int*)p; p += (size_t)N_NODES * CAP * 4;                     // 12.8 MB
    unsigned short* Wt = (unsigned short*)p;                                 // 0.39 MB

    (void)hipMemsetAsync(cnt1, 0, (size_t)2 * N_NODES * 4, stream);

    prep_kernel<<<PREP_BLOCKS, 256, 0, stream>>>(
        x, xb, Ws, W1, W2, Wt, src1, dst1, src2, dst2, cnt1, cnt2, bkt1, bkt2);

    {   // gather-aggregate, one wave per node (both relations)
        long long total = (long long)N_NODES * 64;
        gather_kernel<<<(int)((total + 255) / 256), 256, 0, stream>>>(
            xb, cnt1, cnt2, bkt1, bkt2, xa1, xa2);
    }
    {   // MFMA GEMM + bias + relu, full-N blocks
        gemm_kernel<<<(N_NODES + BM - 1) / BM, 512, 0, stream>>>(
            xb, xa1, xa2, Wt, bias, out);
    }
}